// Round 10
// baseline (320.386 us; speedup 1.0000x reference)
//
#include <hip/hip_runtime.h>
#include <hip/hip_bf16.h>

#define N 4096
#define IN_DIM 256
#define HID 64
#define NHEADS 4
#define OUT_DIM 128
#define LOG2E 1.44269504088896340736f
#define NBLK 512

typedef __attribute__((ext_vector_type(8))) short bf16x8;
typedef __attribute__((ext_vector_type(4))) float f32x4;

// Two-term bf16 split: v ~= hi + lo with |err| ~ 2^-17 |v|.
__device__ __forceinline__ ushort2 bsplit(float v) {
    const ushort h = __hip_bfloat16_raw(__float2bfloat16(v)).x;
    const float vh = __uint_as_float((unsigned)h << 16);
    const ushort l = __hip_bfloat16_raw(__float2bfloat16(v - vh)).x;
    return make_ushort2(h, l);
}

// ---------------------------------------------------------------------------
// Grid barrier, R10 fix of the R2 disaster: R2 spun on an ACQUIRE atomic --
// every poll did agent-scope cache maintenance, 512 blocks continuously
// invalidating the per-XCD L2s (375us kernel, 212GB/s latency-bound).
// Correct pattern: one release fence -> RELAXED add -> RELAXED spin (no cache
// ops) -> one acquire fence. Bounded spin fails loud instead of hanging.
// ---------------------------------------------------------------------------
__device__ __forceinline__ void grid_sync(unsigned* cnt) {
    __syncthreads();
    if (threadIdx.x == 0) {
        __threadfence();                              // release (once)
        __hip_atomic_fetch_add(cnt, 1u, __ATOMIC_RELAXED,
                               __HIP_MEMORY_SCOPE_AGENT);
        int spins = 0;
        while (__hip_atomic_load(cnt, __ATOMIC_RELAXED,
                                 __HIP_MEMORY_SCOPE_AGENT) < NBLK) {
            __builtin_amdgcn_s_sleep(8);
            if (++spins > (1 << 22)) break;           // fail loud, not hung
        }
        __threadfence();                              // acquire (once)
    }
    __syncthreads();
}

// ---------------------------------------------------------------------------
// Fused attention stage (R9 exp-free P-gen, verified):
//   P = exp(lrelu(f1+f2,0.5)) = max(E1*E2, S1*S2).
// C/D layout (verified): col=lane&15, row=quad*4+reg.
// ---------------------------------------------------------------------------
template <int D, int DSL, int G, int MW>
__device__ __forceinline__ void attn_stage(
        const int bx, const int by,
        const unsigned* __restrict__ maskT,
        const __hip_bfloat16* __restrict__ WhB,
        const float* __restrict__ E1g, const float* __restrict__ S1g,
        const float* __restrict__ E2g, const float* __restrict__ S2g,
        float* __restrict__ outp, float* __restrict__ sh,
        float* __restrict__ dsh) {
    constexpr int CTtot = D / 16;
    constexpr int CTT = CTtot / DSL;
    constexpr int CC = (D == 64) ? 1 : 2;
    constexpr int KSTEPS = N / (32 * G);
    const int t = threadIdx.x;
    const int g = t >> 6, lane = t & 63;
    const int m = lane & 15, quad = lane >> 4;
    const int h = by / DSL, slc = by % DSL;
    const int i0 = bx * (16 * MW);

    float e1v[MW], s1v[MW];
#pragma unroll
    for (int mw = 0; mw < MW; mw++) {
        e1v[mw] = E1g[(size_t)h * N + i0 + mw * 16 + m];
        s1v[mw] = S1g[(size_t)h * N + i0 + mw * 16 + m];
    }
    const unsigned* mp = maskT + (size_t)(g * KSTEPS) * N + i0 + m;
    const float* ep = E2g + (size_t)h * N + g * (N / G) + quad * 8;
    const float* sp = S2g + (size_t)h * N + g * (N / G) + quad * 8;
    const bf16x8* bp = (const bf16x8*)WhB +
                       ((size_t)h * (N / 32) * CTtot +
                        (size_t)(g * KSTEPS) * CTtot + slc * CTT) * 64 + lane;

    const f32x4 zero = {0.f, 0.f, 0.f, 0.f};
    f32x4 acc[MW][CTT];
    f32x4 sac[MW];
#pragma unroll
    for (int mw = 0; mw < MW; mw++) {
        sac[mw] = zero;
#pragma unroll
        for (int ct = 0; ct < CTT; ct++) acc[mw][ct] = zero;
    }
    const short one_bf = (short)0x3F80;
    const bf16x8 ones = {one_bf, one_bf, one_bf, one_bf,
                         one_bf, one_bf, one_bf, one_bf};

    unsigned mwrd[2][MW];
    float4 e2lo[2], e2hi[2], s2lo[2], s2hi[2];
    auto stage = [&](int b) {
#pragma unroll
        for (int mw = 0; mw < MW; mw++) mwrd[b][mw] = mp[mw * 16];
        e2lo[b] = *(const float4*)(ep);
        e2hi[b] = *(const float4*)(ep + 4);
        s2lo[b] = *(const float4*)(sp);
        s2hi[b] = *(const float4*)(sp + 4);
    };

    stage(0); mp += N; ep += 32; sp += 32;
#pragma unroll 2
    for (int ks = 0; ks < KSTEPS; ks++) {
        const int cur = ks & 1;
        bf16x8 bfrag[CTT];
#pragma unroll
        for (int ct = 0; ct < CTT; ct++) bfrag[ct] = bp[ct * 64];
        bp += CTtot * 64;
        if (ks + 1 < KSTEPS) { stage(cur ^ 1); mp += N; ep += 32; sp += 32; }
        // ---- P-gen: P = max(E1*E2, S1*S2), no exp ----
        const float Ee[8] = {e2lo[cur].x, e2lo[cur].y, e2lo[cur].z, e2lo[cur].w,
                             e2hi[cur].x, e2hi[cur].y, e2hi[cur].z, e2hi[cur].w};
        const float Se[8] = {s2lo[cur].x, s2lo[cur].y, s2lo[cur].z, s2lo[cur].w,
                             s2hi[cur].x, s2hi[cur].y, s2hi[cur].z, s2hi[cur].w};
        bf16x8 afr[MW];
#pragma unroll
        for (int mw = 0; mw < MW; mw++) {
            const unsigned mword = (mwrd[cur][mw] >> (quad * 8)) & 0xFFu;
            const unsigned spread = mword * 0x8001u;
            float p[8];
#pragma unroll
            for (int e = 0; e < 8; e++)
                p[e] = fmaxf(e1v[mw] * Ee[e], s1v[mw] * Se[e]);
            union { bf16x8 v; unsigned u32[4]; __hip_bfloat162 h2[4]; } u;
#pragma unroll
            for (int e2 = 0; e2 < 4; e2++) {
                u.h2[e2] = __float22bfloat162_rn(
                    make_float2(p[2 * e2], p[2 * e2 + 1]));
                const unsigned mk =
                    ((spread >> (2 * e2)) & 0x00010001u) * 0xFFFFu;
                u.u32[e2] &= mk;
            }
            afr[mw] = u.v;
        }
#pragma unroll
        for (int ct = 0; ct < CTT; ct++)
#pragma unroll
            for (int mw = 0; mw < MW; mw++)
                acc[mw][ct] = __builtin_amdgcn_mfma_f32_16x16x32_bf16(
                    afr[mw], bfrag[ct], acc[mw][ct], 0, 0, 0);
#pragma unroll
        for (int mw = 0; mw < MW; mw++)
            sac[mw] = __builtin_amdgcn_mfma_f32_16x16x32_bf16(
                afr[mw], ones, sac[mw], 0, 0, 0);
    }

    // ---- epilogue: LDS cross-group reduction ----
#pragma unroll
    for (int rd = 0; rd < CTT / CC; rd++) {
#pragma unroll
        for (int mw = 0; mw < MW; mw++) {
#pragma unroll
            for (int cc = 0; cc < CC; cc++) {
#pragma unroll
                for (int r = 0; r < 4; r++)
                    sh[(((mw * G + g) * 16 + quad * 4 + r) * CC + cc) * 17 + m] =
                        acc[mw][rd * CC + cc][r];
            }
            if (rd == 0 && m == 0) {
#pragma unroll
                for (int r = 0; r < 4; r++)
                    dsh[(mw * G + g) * 16 + quad * 4 + r] = sac[mw][r];
            }
        }
        __syncthreads();
        if (t < 16 * CC * 16) {
            int row, chl;
            if (D == 64) { row = t & 15; chl = (t >> 4) & 15; }
            else         { chl = t & 31; row = (t >> 5) & 15; }
#pragma unroll
            for (int mw = 0; mw < MW; mw++) {
                float av = 0.f, ss = 0.f;
#pragma unroll
                for (int gg = 0; gg < G; gg++) {
                    av += sh[(((mw * G + gg) * 16 + row) * CC + (chl >> 4)) * 17 +
                             (chl & 15)];
                    ss += dsh[(mw * G + gg) * 16 + row];
                }
                float v = av / ss;
                v = (v > 0.f) ? v : (__builtin_amdgcn_exp2f(v * LOG2E) - 1.f);
                const int chg = h * D + slc * (CTT * 16) + rd * CC * 16 + chl;
                const int irow = i0 + mw * 16 + row;
                if (D == 64)
                    outp[(size_t)irow * (NHEADS * HID) + chg] = v;  // h1[i][ch]
                else
                    outp[(size_t)irow * D + chg] = v;               // out[i][ch]
            }
        }
        __syncthreads();
    }
}

// ---------------------------------------------------------------------------
// Mega-kernel: 4 stages, 3 grid barriers, one dispatch. 512 blocks x 512 thr
// = 2 blocks/CU (co-resident; lb(512,4) caps VGPR at 128).
//  stage1: mask-pack (1 adj row per wave, 8 waves) + gemm1 (waves 0-1:
//          half-tile = 16 rows x 2 heads, block b -> tile b>>1, heads (b&1)*2+w)
//  stage2: attn1 D=64 MW=2 G=8  (bx=bid&127, by=head=bid>>7)
//  stage3: gemm2 (blocks 0..255, 16 rows x 8 ct-waves) + E/S tables
//  stage4: attn2 D=128 DSL=2 MW=1 G=8 (bx=bid&255, slc=bid>>8)
// ---------------------------------------------------------------------------
__global__ __launch_bounds__(512, 4) void mega(
        const float* __restrict__ x, const float* __restrict__ W,
        const float* __restrict__ a, const int* __restrict__ adj,
        const float* __restrict__ W2, const float* __restrict__ a2,
        __hip_bfloat16* __restrict__ WhB1, __hip_bfloat16* __restrict__ WhB2,
        float* __restrict__ E1a, float* __restrict__ S1a,
        float* __restrict__ E2a, float* __restrict__ S2a,
        float* __restrict__ E1b, float* __restrict__ S1b,
        float* __restrict__ E2b, float* __restrict__ S2b,
        float* __restrict__ h1, unsigned* __restrict__ maskT,
        float* __restrict__ out, unsigned* __restrict__ bars) {
    __shared__ float shbuf[4608];
    __shared__ float dshbuf[256];
    const int t = threadIdx.x;
    const int bid = blockIdx.x;
    const int w = t >> 6, lane = t & 63;

    // ================= stage 1: mask pack + gemm1 =================
    {
        // ---- mask pack: row i = bid*8 + w (bit-spread, verified R6) ----
        const int i = bid * 8 + w;
        const int4* arow = (const int4*)(adj + (size_t)i * N);
        for (int jb = 0; jb < N / 256; jb++) {
            const int4 a4 = arow[jb * 64 + lane];
            unsigned long long bal[4];
            bal[0] = __ballot(a4.x > 0);
            bal[1] = __ballot(a4.y > 0);
            bal[2] = __ballot(a4.z > 0);
            bal[3] = __ballot(a4.w > 0);
            if (lane < 8) {
                unsigned word = 0;
#pragma unroll
                for (int e = 0; e < 4; e++) {
                    unsigned xv = (unsigned)(bal[e] >> (8 * lane)) & 0xFFu;
                    xv = (xv | (xv << 12)) & 0x000F000Fu;
                    xv = (xv | (xv << 6))  & 0x03030303u;
                    xv = (xv | (xv << 3))  & 0x11111111u;
                    word |= xv << e;
                }
                maskT[(size_t)(jb * 8 + lane) * N + i] = word;
            }
        }
        // ---- gemm1 (waves 0-1): head h = (bid&1)*2+w, tile i0 = (bid>>1)*16
        if (w < 2) {
            const int h = (bid & 1) * 2 + w;
            const int m = lane & 15, quad = lane >> 4;
            const int i0 = (bid >> 1) * 16;
            const float* xrow = x + (size_t)(i0 + m) * IN_DIM;
            const float* Wp = W + (size_t)h * IN_DIM * HID;
            const f32x4 zero = {0.f, 0.f, 0.f, 0.f};
            f32x4 acc[4] = {zero, zero, zero, zero};
            for (int ks = 0; ks < 8; ks++) {
                const int kb = ks * 32 + quad * 8;
                const float4 xa = *(const float4*)(xrow + kb);
                const float4 xb = *(const float4*)(xrow + kb + 4);
                const float xf[8] = {xa.x, xa.y, xa.z, xa.w,
                                     xb.x, xb.y, xb.z, xb.w};
                bf16x8 xh, xl;
#pragma unroll
                for (int e = 0; e < 8; e++) {
                    const ushort2 s = bsplit(xf[e]);
                    xh[e] = (short)s.x; xl[e] = (short)s.y;
                }
#pragma unroll
                for (int ct = 0; ct < 4; ct++) {
                    bf16x8 wh, wl;
#pragma unroll
                    for (int e = 0; e < 8; e++) {
                        const ushort2 s =
                            bsplit(Wp[(size_t)(kb + e) * HID + ct * 16 + m]);
                        wh[e] = (short)s.x; wl[e] = (short)s.y;
                    }
                    acc[ct] = __builtin_amdgcn_mfma_f32_16x16x32_bf16(
                        xh, wh, acc[ct], 0, 0, 0);
                    acc[ct] = __builtin_amdgcn_mfma_f32_16x16x32_bf16(
                        xl, wh, acc[ct], 0, 0, 0);
                    acc[ct] = __builtin_amdgcn_mfma_f32_16x16x32_bf16(
                        xh, wl, acc[ct], 0, 0, 0);
                }
            }
            const int jblk = i0 >> 5, jb2 = (i0 >> 4) & 1;
#pragma unroll
            for (int ct = 0; ct < 4; ct++) {
#pragma unroll
                for (int r = 0; r < 4; r++) {
                    const int jo = quad * 4 + r;
                    const int lane_idx = m + 16 * (2 * jb2 + (jo >> 3));
                    WhB1[((((size_t)h * (N / 32) + jblk) * 4 + ct) * 64 +
                          lane_idx) * 8 + (jo & 7)] = __float2bfloat16(acc[ct][r]);
                }
            }
            float av1[4], av2[4];
#pragma unroll
            for (int ct = 0; ct < 4; ct++) {
                av1[ct] = a[h * 2 * HID + ct * 16 + m];
                av2[ct] = a[h * 2 * HID + HID + ct * 16 + m];
            }
            float s1[4], s2[4];
#pragma unroll
            for (int r = 0; r < 4; r++) {
                s1[r] = 0.f; s2[r] = 0.f;
#pragma unroll
                for (int ct = 0; ct < 4; ct++) {
                    s1[r] += acc[ct][r] * av1[ct];
                    s2[r] += acc[ct][r] * av2[ct];
                }
            }
#pragma unroll
            for (int mm = 8; mm > 0; mm >>= 1) {
#pragma unroll
                for (int r = 0; r < 4; r++) {
                    s1[r] += __shfl_xor(s1[r], mm, 64);
                    s2[r] += __shfl_xor(s2[r], mm, 64);
                }
            }
            if (m == 0) {
#pragma unroll
                for (int r = 0; r < 4; r++) {
                    const size_t ix = (size_t)h * N + i0 + quad * 4 + r;
                    E1a[ix] = __builtin_amdgcn_exp2f(s1[r] * LOG2E);
                    S1a[ix] = __builtin_amdgcn_exp2f(s1[r] * (0.5f * LOG2E));
                    E2a[ix] = __builtin_amdgcn_exp2f(s2[r] * LOG2E);
                    S2a[ix] = __builtin_amdgcn_exp2f(s2[r] * (0.5f * LOG2E));
                }
            }
        }
    }
    grid_sync(bars + 0);

    // ================= stage 2: attention layer 1 =================
    attn_stage<HID, 1, 8, 2>(bid & 127, bid >> 7, maskT, WhB1,
                             E1a, S1a, E2a, S2a, h1, shbuf, dshbuf);
    grid_sync(bars + 1);

    // ================= stage 3: gemm2 (blocks 0..255) =================
    if (bid < 256) {
        const int m = lane & 15, quad = lane >> 4;
        const int i0 = bid * 16;
        const float* arow = h1 + (size_t)(i0 + m) * IN_DIM;
        const float* wp = W2 + w * 16 + m;
        const f32x4 zero = {0.f, 0.f, 0.f, 0.f};
        f32x4 acc = zero;
        for (int ks = 0; ks < 8; ks++) {
            const int kb = ks * 32 + quad * 8;
            const float4 xa = *(const float4*)(arow + kb);
            const float4 xb = *(const float4*)(arow + kb + 4);
            const float xf[8] = {xa.x, xa.y, xa.z, xa.w, xb.x, xb.y, xb.z, xb.w};
            bf16x8 xh, xl, wh, wl;
#pragma unroll
            for (int e = 0; e < 8; e++) {
                const ushort2 s = bsplit(xf[e]);
                xh[e] = (short)s.x; xl[e] = (short)s.y;
            }
#pragma unroll
            for (int e = 0; e < 8; e++) {
                const ushort2 s = bsplit(wp[(size_t)(kb + e) * OUT_DIM]);
                wh[e] = (short)s.x; wl[e] = (short)s.y;
            }
            acc = __builtin_amdgcn_mfma_f32_16x16x32_bf16(xh, wh, acc, 0, 0, 0);
            acc = __builtin_amdgcn_mfma_f32_16x16x32_bf16(xl, wh, acc, 0, 0, 0);
            acc = __builtin_amdgcn_mfma_f32_16x16x32_bf16(xh, wl, acc, 0, 0, 0);
        }
        const int jblk = i0 >> 5, jb2 = (i0 >> 4) & 1;
#pragma unroll
        for (int r = 0; r < 4; r++) {
            const int jo = quad * 4 + r;
            const int lane_idx = m + 16 * (2 * jb2 + (jo >> 3));
            WhB2[(((size_t)jblk * 8 + w) * 64 + lane_idx) * 8 + (jo & 7)] =
                __float2bfloat16(acc[r]);
        }
        const float av1 = a2[w * 16 + m], av2 = a2[OUT_DIM + w * 16 + m];
        float s1[4], s2[4];
#pragma unroll
        for (int r = 0; r < 4; r++) { s1[r] = acc[r] * av1; s2[r] = acc[r] * av2; }
#pragma unroll
        for (int mm = 8; mm > 0; mm >>= 1) {
#pragma unroll
            for (int r = 0; r < 4; r++) {
                s1[r] += __shfl_xor(s1[r], mm, 64);
                s2[r] += __shfl_xor(s2[r], mm, 64);
            }
        }
        if (m == 0) {
#pragma unroll
            for (int r = 0; r < 4; r++) {
                dshbuf[((w * 16) + quad * 4 + r) * 2 + 0] = s1[r];
                dshbuf[((w * 16) + quad * 4 + r) * 2 + 1] = s2[r];
            }
        }
        __syncthreads();
        if (t < 32) {
            const int row = t & 15, fn = t >> 4;
            float s = 0.f;
#pragma unroll
            for (int w8 = 0; w8 < 8; w8++) s += dshbuf[(w8 * 16 + row) * 2 + fn];
            const float e = __builtin_amdgcn_exp2f(s * LOG2E);
            const float sq = __builtin_amdgcn_exp2f(s * (0.5f * LOG2E));
            if (fn) { E2b[i0 + row] = e; S2b[i0 + row] = sq; }
            else    { E1b[i0 + row] = e; S1b[i0 + row] = sq; }
        }
    }
    grid_sync(bars + 2);

    // ================= stage 4: attention layer 2 =================
    attn_stage<OUT_DIM, 2, 8, 1>(bid & 255, bid >> 8, maskT, WhB2,
                                 E1b, S1b, E2b, S2b, out, shbuf, dshbuf);
}

// ---------------------------------------------------------------------------
extern "C" void kernel_launch(void* const* d_in, const int* in_sizes, int n_in,
                              void* d_out, int out_size, void* d_ws, size_t ws_size,
                              hipStream_t stream) {
    const float* x   = (const float*)d_in[0];
    const int*   adj = (const int*)d_in[1];
    const float* Wh_ = (const float*)d_in[2];
    const float* ah  = (const float*)d_in[3];
    const float* W2  = (const float*)d_in[4];
    const float* a2  = (const float*)d_in[5];
    float* out = (float*)d_out;

    float* ws = (float*)d_ws;
    float* E1a = ws;                                    // 4*N each
    float* S1a = E1a + (size_t)NHEADS * N;
    float* E2a = S1a + (size_t)NHEADS * N;
    float* S2a = E2a + (size_t)NHEADS * N;
    float* E1b = S2a + (size_t)NHEADS * N;              // N each
    float* S1b = E1b + N;
    float* E2b = S1b + N;
    float* S2b = E2b + N;
    float* h1  = S2b + N;                               // N*256 fp32 (4MB)
    __hip_bfloat16* WhB1 = (__hip_bfloat16*)(h1 + (size_t)IN_DIM * N);  // 2MB
    __hip_bfloat16* WhB2 = WhB1 + (size_t)NHEADS * HID * N;            // 1MB
    unsigned* maskT = (unsigned*)(WhB2 + (size_t)OUT_DIM * N);         // 2MB
    unsigned* bars = maskT + (size_t)(N / 32) * N;                     // 3 ctrs

    hipMemsetAsync(bars, 0, 3 * sizeof(unsigned), stream);
    mega<<<NBLK, 512, 0, stream>>>(x, Wh_, ah, adj, W2, a2, WhB1, WhB2,
                                   E1a, S1a, E2a, S2a, E1b, S1b, E2b, S2b,
                                   h1, maskT, out, bars);
}

// Round 11
// 167.663 us; speedup vs baseline: 1.9109x; 1.9109x over previous
//
#include <hip/hip_runtime.h>
#include <hip/hip_bf16.h>

#define N 4096
#define IN_DIM 256
#define HID 64
#define NHEADS 4
#define OUT_DIM 128
#define LOG2E 1.44269504088896340736f

typedef __attribute__((ext_vector_type(8))) short bf16x8;
typedef __attribute__((ext_vector_type(4))) float f32x4;

// Two-term bf16 split: v ~= hi + lo with |err| ~ 2^-17 |v|.
__device__ __forceinline__ ushort2 bsplit(float v) {
    const ushort h = __hip_bfloat16_raw(__float2bfloat16(v)).x;
    const float vh = __uint_as_float((unsigned)h << 16);
    const ushort l = __hip_bfloat16_raw(__float2bfloat16(v - vh)).x;
    return make_ushort2(h, l);
}

// ---------------------------------------------------------------------------
// prep_kernel = gemm1-MFMA (blocks 0..255) + mask pack (blocks 256..1279).
// R11: row table is C1 = e^(-f1/2) only -- E1 cancels in the softmax ratio
// (h = (P@Wh)/(P@1) is row-scale invariant), so attention P-gen is
// P' = max(E2[j], C1_i * S2[j]): 1 mul + 1 max per element.
// ---------------------------------------------------------------------------
__global__ __launch_bounds__(256, 4) void prep_kernel(
        const float* __restrict__ x, const float* __restrict__ W,
        const float* __restrict__ a, const int* __restrict__ adj,
        __hip_bfloat16* __restrict__ WhB,
        float* __restrict__ C1, float* __restrict__ E2, float* __restrict__ S2,
        unsigned* __restrict__ maskT) {
    const int t = threadIdx.x;
    if (blockIdx.x < 256) {
        // ---------------- gemm1 via MFMA ----------------
        const int h = t >> 6, lane = t & 63, m = lane & 15, quad = lane >> 4;
        const int i0 = blockIdx.x * 16;
        const float* xrow = x + (size_t)(i0 + m) * IN_DIM;
        const float* Wp = W + (size_t)h * IN_DIM * HID;
        const f32x4 zero = {0.f, 0.f, 0.f, 0.f};
        f32x4 acc[4] = {zero, zero, zero, zero};
        for (int ks = 0; ks < 8; ks++) {
            const int kb = ks * 32 + quad * 8;
            const float4 xa = *(const float4*)(xrow + kb);
            const float4 xb = *(const float4*)(xrow + kb + 4);
            const float xf[8] = {xa.x, xa.y, xa.z, xa.w, xb.x, xb.y, xb.z, xb.w};
            bf16x8 xh, xl;
#pragma unroll
            for (int e = 0; e < 8; e++) {
                const ushort2 s = bsplit(xf[e]);
                xh[e] = (short)s.x; xl[e] = (short)s.y;
            }
#pragma unroll
            for (int ct = 0; ct < 4; ct++) {
                bf16x8 wh, wl;
#pragma unroll
                for (int e = 0; e < 8; e++) {
                    const ushort2 s =
                        bsplit(Wp[(size_t)(kb + e) * HID + ct * 16 + m]);
                    wh[e] = (short)s.x; wl[e] = (short)s.y;
                }
                acc[ct] = __builtin_amdgcn_mfma_f32_16x16x32_bf16(
                    xh, wh, acc[ct], 0, 0, 0);
                acc[ct] = __builtin_amdgcn_mfma_f32_16x16x32_bf16(
                    xl, wh, acc[ct], 0, 0, 0);
                acc[ct] = __builtin_amdgcn_mfma_f32_16x16x32_bf16(
                    xh, wl, acc[ct], 0, 0, 0);
            }
        }
        // ---- WhB1 frag store: j = i0+quad*4+r, c = ct*16+m ----
        const int jblk = i0 >> 5, jb2 = (i0 >> 4) & 1;
#pragma unroll
        for (int ct = 0; ct < 4; ct++) {
#pragma unroll
            for (int r = 0; r < 4; r++) {
                const int jo = quad * 4 + r;
                const int lane_idx = m + 16 * (2 * jb2 + (jo >> 3));
                WhB[((((size_t)h * (N / 32) + jblk) * 4 + ct) * 64 + lane_idx) *
                        8 + (jo & 7)] = __float2bfloat16(acc[ct][r]);
            }
        }
        // ---- f1/f2 -> C1 / E2,S2 tables ----
        float av1[4], av2[4];
#pragma unroll
        for (int ct = 0; ct < 4; ct++) {
            av1[ct] = a[h * 2 * HID + ct * 16 + m];
            av2[ct] = a[h * 2 * HID + HID + ct * 16 + m];
        }
        float s1[4], s2[4];
#pragma unroll
        for (int r = 0; r < 4; r++) {
            s1[r] = 0.f; s2[r] = 0.f;
#pragma unroll
            for (int ct = 0; ct < 4; ct++) {
                s1[r] += acc[ct][r] * av1[ct];
                s2[r] += acc[ct][r] * av2[ct];
            }
        }
#pragma unroll
        for (int mm = 8; mm > 0; mm >>= 1) {
#pragma unroll
            for (int r = 0; r < 4; r++) {
                s1[r] += __shfl_xor(s1[r], mm, 64);
                s2[r] += __shfl_xor(s2[r], mm, 64);
            }
        }
        if (m == 0) {
#pragma unroll
            for (int r = 0; r < 4; r++) {
                const size_t ix = (size_t)h * N + i0 + quad * 4 + r;
                C1[ix] = __builtin_amdgcn_exp2f(s1[r] * (-0.5f * LOG2E));
                E2[ix] = __builtin_amdgcn_exp2f(s2[r] * LOG2E);
                S2[ix] = __builtin_amdgcn_exp2f(s2[r] * (0.5f * LOG2E));
            }
        }
    } else {
        // ---------------- mask pack (bit-spread, verified R6) ----------------
        const int lane = t & 63, w = t >> 6;
        const int i = (blockIdx.x - 256) * 4 + w;      // one row per wave
        const int4* arow = (const int4*)(adj + (size_t)i * N);
        for (int jb = 0; jb < N / 256; jb++) {
            const int4 a4 = arow[jb * 64 + lane];
            unsigned long long bal[4];
            bal[0] = __ballot(a4.x > 0);
            bal[1] = __ballot(a4.y > 0);
            bal[2] = __ballot(a4.z > 0);
            bal[3] = __ballot(a4.w > 0);
            if (lane < 8) {
                unsigned word = 0;
#pragma unroll
                for (int e = 0; e < 4; e++) {
                    unsigned xv = (unsigned)(bal[e] >> (8 * lane)) & 0xFFu;
                    xv = (xv | (xv << 12)) & 0x000F000Fu;
                    xv = (xv | (xv << 6))  & 0x03030303u;
                    xv = (xv | (xv << 3))  & 0x11111111u;
                    word |= xv << e;
                }
                maskT[(size_t)(jb * 8 + lane) * N + i] = word;
            }
        }
    }
}

// ---------------------------------------------------------------------------
// Fused attention layer, R11:
//  (a) E1-cancelled P-gen: P' = max(E2[j], C1_i*S2[j]) -- softmax ratio
//      identical (row scale cancels), 1 mul + 1 max per element.
//  (b) B-fragments double-buffered: loads for ks+1 issued before P-gen of ks
//      (~1 full iteration ahead), hiding the ~200cy L2 latency that a
//      same-iteration load can't (MFMA consumed bfrag ~140cy after issue).
// Configs (measured-best R7): L1 HEADS=4,D=64,G=8,MW=2 grid(128,4) 512thr;
//                             L2 HEADS=1,D=128,G=8,MW=1 grid(256,1) 512thr.
// Mask applied as bitwise AND on packed bf16 pairs (bit-exact, verified R7).
// ---------------------------------------------------------------------------
template <int HEADS, int D, int DSL, int G, int MW, int OCC>
__global__ __launch_bounds__(G * 64, OCC) void attn_fused(
        const unsigned* __restrict__ maskT,             // [N/32][N]
        const __hip_bfloat16* __restrict__ WhB,          // [H][N/32][D/16][64][8]
        const float* __restrict__ C1g, const float* __restrict__ E2g,
        const float* __restrict__ S2g,
        float* __restrict__ outp) {
    constexpr int CTtot = D / 16;
    constexpr int CTT = CTtot / DSL;
    constexpr int CC = (D == 64) ? 1 : 2;
    constexpr int KSTEPS = N / (32 * G);
    __shared__ float sh[MW * G * 16 * CC * 17];
    __shared__ float dsh[MW * G * 16];
    const int t = threadIdx.x;
    const int g = t >> 6, lane = t & 63;
    const int m = lane & 15, quad = lane >> 4;
    const int h = blockIdx.y / DSL, slc = blockIdx.y % DSL;
    const int i0 = blockIdx.x * (16 * MW);

    float c1v[MW];
#pragma unroll
    for (int mw = 0; mw < MW; mw++)
        c1v[mw] = C1g[(size_t)h * N + i0 + mw * 16 + m];

    // strength-reduced stream pointers
    const unsigned* mp = maskT + (size_t)(g * KSTEPS) * N + i0 + m;
    const float* ep = E2g + (size_t)h * N + g * (N / G) + quad * 8;
    const float* sp = S2g + (size_t)h * N + g * (N / G) + quad * 8;
    const bf16x8* bp = (const bf16x8*)WhB +
                       ((size_t)h * (N / 32) * CTtot +
                        (size_t)(g * KSTEPS) * CTtot + slc * CTT) * 64 + lane;

    const f32x4 zero = {0.f, 0.f, 0.f, 0.f};
    f32x4 acc[MW][CTT];
    f32x4 sac[MW];
#pragma unroll
    for (int mw = 0; mw < MW; mw++) {
        sac[mw] = zero;
#pragma unroll
        for (int ct = 0; ct < CTT; ct++) acc[mw][ct] = zero;
    }
    const short one_bf = (short)0x3F80;
    const bf16x8 ones = {one_bf, one_bf, one_bf, one_bf,
                         one_bf, one_bf, one_bf, one_bf};

    unsigned mwrd[2][MW];
    float4 e2lo[2], e2hi[2], s2lo[2], s2hi[2];
    bf16x8 bfrag[2][CTT];
    auto stage_mf = [&](int b) {
#pragma unroll
        for (int mw = 0; mw < MW; mw++) mwrd[b][mw] = mp[mw * 16];
        e2lo[b] = *(const float4*)(ep);
        e2hi[b] = *(const float4*)(ep + 4);
        s2lo[b] = *(const float4*)(sp);
        s2hi[b] = *(const float4*)(sp + 4);
    };
    auto load_b = [&](int b) {
#pragma unroll
        for (int ct = 0; ct < CTT; ct++) bfrag[b][ct] = bp[ct * 64];
        bp += CTtot * 64;
    };

    load_b(0);
    stage_mf(0); mp += N; ep += 32; sp += 32;
#pragma unroll 2
    for (int ks = 0; ks < KSTEPS; ks++) {
        const int cur = ks & 1;
        // ---- next-step loads issued first: hidden under P-gen + MFMA ----
        if (ks + 1 < KSTEPS) {
            load_b(cur ^ 1);
            stage_mf(cur ^ 1); mp += N; ep += 32; sp += 32;
        }
        // ---- P-gen: P' = max(E2, C1*S2) ----
        const float Ee[8] = {e2lo[cur].x, e2lo[cur].y, e2lo[cur].z, e2lo[cur].w,
                             e2hi[cur].x, e2hi[cur].y, e2hi[cur].z, e2hi[cur].w};
        const float Se[8] = {s2lo[cur].x, s2lo[cur].y, s2lo[cur].z, s2lo[cur].w,
                             s2hi[cur].x, s2hi[cur].y, s2hi[cur].z, s2hi[cur].w};
        bf16x8 afr[MW];
#pragma unroll
        for (int mw = 0; mw < MW; mw++) {
            const unsigned mword = (mwrd[cur][mw] >> (quad * 8)) & 0xFFu;
            const unsigned spread = mword * 0x8001u;
            float p[8];
#pragma unroll
            for (int e = 0; e < 8; e++)
                p[e] = fmaxf(Ee[e], c1v[mw] * Se[e]);
            union { bf16x8 v; unsigned u32[4]; __hip_bfloat162 h2[4]; } u;
#pragma unroll
            for (int e2 = 0; e2 < 4; e2++) {
                u.h2[e2] = __float22bfloat162_rn(
                    make_float2(p[2 * e2], p[2 * e2 + 1]));
                const unsigned mk =
                    ((spread >> (2 * e2)) & 0x00010001u) * 0xFFFFu;
                u.u32[e2] &= mk;
            }
            afr[mw] = u.v;
        }
        // ---- MFMAs (B amortized across MW row-tiles) ----
#pragma unroll
        for (int ct = 0; ct < CTT; ct++)
#pragma unroll
            for (int mw = 0; mw < MW; mw++)
                acc[mw][ct] = __builtin_amdgcn_mfma_f32_16x16x32_bf16(
                    afr[mw], bfrag[cur][ct], acc[mw][ct], 0, 0, 0);
#pragma unroll
        for (int mw = 0; mw < MW; mw++)
            sac[mw] = __builtin_amdgcn_mfma_f32_16x16x32_bf16(
                afr[mw], ones, sac[mw], 0, 0, 0);
    }

    // ---- epilogue: LDS cross-group reduction ----
#pragma unroll
    for (int rd = 0; rd < CTT / CC; rd++) {
#pragma unroll
        for (int mw = 0; mw < MW; mw++) {
#pragma unroll
            for (int cc = 0; cc < CC; cc++) {
#pragma unroll
                for (int r = 0; r < 4; r++)
                    sh[(((mw * G + g) * 16 + quad * 4 + r) * CC + cc) * 17 + m] =
                        acc[mw][rd * CC + cc][r];
            }
            if (rd == 0 && m == 0) {
#pragma unroll
                for (int r = 0; r < 4; r++)
                    dsh[(mw * G + g) * 16 + quad * 4 + r] = sac[mw][r];
            }
        }
        __syncthreads();
        if (t < 16 * CC * 16) {
            int row, chl;
            if (D == 64) { row = t & 15; chl = (t >> 4) & 15; }
            else         { chl = t & 31; row = (t >> 5) & 15; }
#pragma unroll
            for (int mw = 0; mw < MW; mw++) {
                float av = 0.f, ss = 0.f;
#pragma unroll
                for (int gg = 0; gg < G; gg++) {
                    av += sh[(((mw * G + gg) * 16 + row) * CC + (chl >> 4)) * 17 +
                             (chl & 15)];
                    ss += dsh[(mw * G + gg) * 16 + row];
                }
                float v = av / ss;
                v = (v > 0.f) ? v : (__builtin_amdgcn_exp2f(v * LOG2E) - 1.f);
                const int chg = h * D + slc * (CTT * 16) + rd * CC * 16 + chl;
                const int irow = i0 + mw * 16 + row;
                if (D == 64)
                    outp[(size_t)irow * (NHEADS * HID) + chg] = v;  // h1[i][ch]
                else
                    outp[(size_t)irow * D + chg] = v;               // out[i][ch]
            }
        }
        __syncthreads();
    }
}

// ---------------------------------------------------------------------------
// gemm2 via MFMA bf16-split: h1[4096][256] @ W2[256][128].
// R11 tail: writes C1b / E2b / S2b for the E1-cancelled layer-2 P-gen.
// ---------------------------------------------------------------------------
__global__ __launch_bounds__(512, 2) void gemm2_kernel(
        const float* __restrict__ h1, const float* __restrict__ W2,
        const float* __restrict__ a2, __hip_bfloat16* __restrict__ WhB2,
        float* __restrict__ C1, float* __restrict__ E2, float* __restrict__ S2) {
    __shared__ float fred[8][16][2];
    const int t = threadIdx.x;
    const int w = t >> 6, lane = t & 63, m = lane & 15, quad = lane >> 4;
    const int i0 = blockIdx.x * 16;
    const float* arow = h1 + (size_t)(i0 + m) * IN_DIM;
    const float* wp = W2 + w * 16 + m;
    const f32x4 zero = {0.f, 0.f, 0.f, 0.f};
    f32x4 acc = zero;
    for (int ks = 0; ks < 8; ks++) {
        const int kb = ks * 32 + quad * 8;
        const float4 xa = *(const float4*)(arow + kb);
        const float4 xb = *(const float4*)(arow + kb + 4);
        const float xf[8] = {xa.x, xa.y, xa.z, xa.w, xb.x, xb.y, xb.z, xb.w};
        bf16x8 xh, xl, wh, wl;
#pragma unroll
        for (int e = 0; e < 8; e++) {
            const ushort2 s = bsplit(xf[e]);
            xh[e] = (short)s.x; xl[e] = (short)s.y;
        }
#pragma unroll
        for (int e = 0; e < 8; e++) {
            const ushort2 s = bsplit(wp[(size_t)(kb + e) * OUT_DIM]);
            wh[e] = (short)s.x; wl[e] = (short)s.y;
        }
        acc = __builtin_amdgcn_mfma_f32_16x16x32_bf16(xh, wh, acc, 0, 0, 0);
        acc = __builtin_amdgcn_mfma_f32_16x16x32_bf16(xl, wh, acc, 0, 0, 0);
        acc = __builtin_amdgcn_mfma_f32_16x16x32_bf16(xh, wl, acc, 0, 0, 0);
    }
    const int jblk = i0 >> 5, jb2 = (i0 >> 4) & 1;
#pragma unroll
    for (int r = 0; r < 4; r++) {
        const int jo = quad * 4 + r;
        const int lane_idx = m + 16 * (2 * jb2 + (jo >> 3));
        WhB2[(((size_t)jblk * 8 + w) * 64 + lane_idx) * 8 + (jo & 7)] =
            __float2bfloat16(acc[r]);
    }
    const float av1 = a2[w * 16 + m], av2 = a2[OUT_DIM + w * 16 + m];
    float s1[4], s2[4];
#pragma unroll
    for (int r = 0; r < 4; r++) { s1[r] = acc[r] * av1; s2[r] = acc[r] * av2; }
#pragma unroll
    for (int mm = 8; mm > 0; mm >>= 1) {
#pragma unroll
        for (int r = 0; r < 4; r++) {
            s1[r] += __shfl_xor(s1[r], mm, 64);
            s2[r] += __shfl_xor(s2[r], mm, 64);
        }
    }
    if (m == 0) {
#pragma unroll
        for (int r = 0; r < 4; r++) {
            fred[w][quad * 4 + r][0] = s1[r];
            fred[w][quad * 4 + r][1] = s2[r];
        }
    }
    __syncthreads();
    if (t < 32) {
        const int row = t & 15, fn = t >> 4;
        float s = 0.f;
#pragma unroll
        for (int w8 = 0; w8 < 8; w8++) s += fred[w8][row][fn];
        if (fn) {
            E2[i0 + row] = __builtin_amdgcn_exp2f(s * LOG2E);
            S2[i0 + row] = __builtin_amdgcn_exp2f(s * (0.5f * LOG2E));
        } else {
            C1[i0 + row] = __builtin_amdgcn_exp2f(s * (-0.5f * LOG2E));
        }
    }
}

// ---------------------------------------------------------------------------
extern "C" void kernel_launch(void* const* d_in, const int* in_sizes, int n_in,
                              void* d_out, int out_size, void* d_ws, size_t ws_size,
                              hipStream_t stream) {
    const float* x   = (const float*)d_in[0];
    const int*   adj = (const int*)d_in[1];
    const float* Wh_ = (const float*)d_in[2];
    const float* ah  = (const float*)d_in[3];
    const float* W2  = (const float*)d_in[4];
    const float* a2  = (const float*)d_in[5];
    float* out = (float*)d_out;

    float* ws = (float*)d_ws;
    float* C1a = ws;                                    // 4*N each
    float* E2a = C1a + (size_t)NHEADS * N;
    float* S2a = E2a + (size_t)NHEADS * N;
    float* C1b = S2a + (size_t)NHEADS * N;              // N each
    float* E2b = C1b + N;
    float* S2b = E2b + N;
    float* h1  = S2b + N;                               // N*256 fp32 (4MB)
    __hip_bfloat16* WhB1 = (__hip_bfloat16*)(h1 + (size_t)IN_DIM * N);  // 2MB
    __hip_bfloat16* WhB2 = WhB1 + (size_t)NHEADS * HID * N;            // 1MB
    unsigned* maskT = (unsigned*)(WhB2 + (size_t)OUT_DIM * N);         // 2MB

    prep_kernel<<<1280, 256, 0, stream>>>(x, Wh_, ah, adj, WhB1,
                                          C1a, E2a, S2a, maskT);
    attn_fused<NHEADS, HID, 1, 8, 2, 2>
        <<<dim3(N / 32, NHEADS), 512, 0, stream>>>(maskT, WhB1,
                                                   C1a, E2a, S2a, h1);
    gemm2_kernel<<<N / 16, 512, 0, stream>>>(h1, W2, a2, WhB2,
                                             C1b, E2b, S2b);
    attn_fused<1, OUT_DIM, 1, 8, 1, 2>
        <<<dim3(N / 16, 1), 512, 0, stream>>>(maskT, WhB2,
                                              C1b, E2b, S2b, out);
}

// Round 12
// 167.185 us; speedup vs baseline: 1.9164x; 1.0029x over previous
//
#include <hip/hip_runtime.h>
#include <hip/hip_bf16.h>

#define N 4096
#define IN_DIM 256
#define HID 64
#define NHEADS 4
#define OUT_DIM 128
#define LOG2E 1.44269504088896340736f

typedef __attribute__((ext_vector_type(8))) short bf16x8;
typedef __attribute__((ext_vector_type(4))) float f32x4;

// Two-term bf16 split: v ~= hi + lo with |err| ~ 2^-17 |v|.
__device__ __forceinline__ ushort2 bsplit(float v) {
    const ushort h = __hip_bfloat16_raw(__float2bfloat16(v)).x;
    const float vh = __uint_as_float((unsigned)h << 16);
    const ushort l = __hip_bfloat16_raw(__float2bfloat16(v - vh)).x;
    return make_ushort2(h, l);
}

// ---------------------------------------------------------------------------
// prep_kernel = gemm1-MFMA (blocks 0..255) + mask pack (blocks 256..1279).
// Row table C1 = e^(-f1/2); attention P-gen is P' = max(E2[j], C1_i*S2[j])
// (E1 cancels in the softmax ratio -- verified R11).
// ---------------------------------------------------------------------------
__global__ __launch_bounds__(256, 4) void prep_kernel(
        const float* __restrict__ x, const float* __restrict__ W,
        const float* __restrict__ a, const int* __restrict__ adj,
        __hip_bfloat16* __restrict__ WhB,
        float* __restrict__ C1, float* __restrict__ E2, float* __restrict__ S2,
        unsigned* __restrict__ maskT) {
    const int t = threadIdx.x;
    if (blockIdx.x < 256) {
        // ---------------- gemm1 via MFMA ----------------
        const int h = t >> 6, lane = t & 63, m = lane & 15, quad = lane >> 4;
        const int i0 = blockIdx.x * 16;
        const float* xrow = x + (size_t)(i0 + m) * IN_DIM;
        const float* Wp = W + (size_t)h * IN_DIM * HID;
        const f32x4 zero = {0.f, 0.f, 0.f, 0.f};
        f32x4 acc[4] = {zero, zero, zero, zero};
        for (int ks = 0; ks < 8; ks++) {
            const int kb = ks * 32 + quad * 8;
            const float4 xa = *(const float4*)(xrow + kb);
            const float4 xb = *(const float4*)(xrow + kb + 4);
            const float xf[8] = {xa.x, xa.y, xa.z, xa.w, xb.x, xb.y, xb.z, xb.w};
            bf16x8 xh, xl;
#pragma unroll
            for (int e = 0; e < 8; e++) {
                const ushort2 s = bsplit(xf[e]);
                xh[e] = (short)s.x; xl[e] = (short)s.y;
            }
#pragma unroll
            for (int ct = 0; ct < 4; ct++) {
                bf16x8 wh, wl;
#pragma unroll
                for (int e = 0; e < 8; e++) {
                    const ushort2 s =
                        bsplit(Wp[(size_t)(kb + e) * HID + ct * 16 + m]);
                    wh[e] = (short)s.x; wl[e] = (short)s.y;
                }
                acc[ct] = __builtin_amdgcn_mfma_f32_16x16x32_bf16(
                    xh, wh, acc[ct], 0, 0, 0);
                acc[ct] = __builtin_amdgcn_mfma_f32_16x16x32_bf16(
                    xl, wh, acc[ct], 0, 0, 0);
                acc[ct] = __builtin_amdgcn_mfma_f32_16x16x32_bf16(
                    xh, wl, acc[ct], 0, 0, 0);
            }
        }
        // ---- WhB1 frag store: j = i0+quad*4+r, c = ct*16+m ----
        const int jblk = i0 >> 5, jb2 = (i0 >> 4) & 1;
#pragma unroll
        for (int ct = 0; ct < 4; ct++) {
#pragma unroll
            for (int r = 0; r < 4; r++) {
                const int jo = quad * 4 + r;
                const int lane_idx = m + 16 * (2 * jb2 + (jo >> 3));
                WhB[((((size_t)h * (N / 32) + jblk) * 4 + ct) * 64 + lane_idx) *
                        8 + (jo & 7)] = __float2bfloat16(acc[ct][r]);
            }
        }
        // ---- f1/f2 -> C1 / E2,S2 tables ----
        float av1[4], av2[4];
#pragma unroll
        for (int ct = 0; ct < 4; ct++) {
            av1[ct] = a[h * 2 * HID + ct * 16 + m];
            av2[ct] = a[h * 2 * HID + HID + ct * 16 + m];
        }
        float s1[4], s2[4];
#pragma unroll
        for (int r = 0; r < 4; r++) {
            s1[r] = 0.f; s2[r] = 0.f;
#pragma unroll
            for (int ct = 0; ct < 4; ct++) {
                s1[r] += acc[ct][r] * av1[ct];
                s2[r] += acc[ct][r] * av2[ct];
            }
        }
#pragma unroll
        for (int mm = 8; mm > 0; mm >>= 1) {
#pragma unroll
            for (int r = 0; r < 4; r++) {
                s1[r] += __shfl_xor(s1[r], mm, 64);
                s2[r] += __shfl_xor(s2[r], mm, 64);
            }
        }
        if (m == 0) {
#pragma unroll
            for (int r = 0; r < 4; r++) {
                const size_t ix = (size_t)h * N + i0 + quad * 4 + r;
                C1[ix] = __builtin_amdgcn_exp2f(s1[r] * (-0.5f * LOG2E));
                E2[ix] = __builtin_amdgcn_exp2f(s2[r] * LOG2E);
                S2[ix] = __builtin_amdgcn_exp2f(s2[r] * (0.5f * LOG2E));
            }
        }
    } else {
        // ---------------- mask pack (bit-spread, verified R6) ----------------
        const int lane = t & 63, w = t >> 6;
        const int i = (blockIdx.x - 256) * 4 + w;      // one row per wave
        const int4* arow = (const int4*)(adj + (size_t)i * N);
        for (int jb = 0; jb < N / 256; jb++) {
            const int4 a4 = arow[jb * 64 + lane];
            unsigned long long bal[4];
            bal[0] = __ballot(a4.x > 0);
            bal[1] = __ballot(a4.y > 0);
            bal[2] = __ballot(a4.z > 0);
            bal[3] = __ballot(a4.w > 0);
            if (lane < 8) {
                unsigned word = 0;
#pragma unroll
                for (int e = 0; e < 4; e++) {
                    unsigned xv = (unsigned)(bal[e] >> (8 * lane)) & 0xFFu;
                    xv = (xv | (xv << 12)) & 0x000F000Fu;
                    xv = (xv | (xv << 6))  & 0x03030303u;
                    xv = (xv | (xv << 3))  & 0x11111111u;
                    word |= xv << e;
                }
                maskT[(size_t)(jb * 8 + lane) * N + i] = word;
            }
        }
    }
}

// ---------------------------------------------------------------------------
// Fused attention layer, R12: STATIC double-buffering (rule-#20 fix).
// Previous versions indexed pipeline state by cur=ks&1 at RUNTIME
// (mwrd[cur][..], bfrag[cur][ct]) -- runtime-indexed register arrays get
// demoted to scratch (localMem), explaining the measured ~5x VALU-instruction
// inflation (357 vs ~74 per wave-K-step) and VGPR_Count=64. Fix: named A/B
// buffers, loop advances by 2 K-steps, every index compile-time. Generic
// lambda (auto&) keeps array identity so SROA keeps state in registers.
// P-gen: P' = max(E2[j], C1_i*S2[j]) (E1 cancels in softmax ratio, R11).
// Mask applied as bitwise AND on packed bf16 pairs (bit-exact, R7).
// ---------------------------------------------------------------------------
template <int HEADS, int D, int DSL, int G, int MW, int OCC>
__global__ __launch_bounds__(G * 64, OCC) void attn_fused(
        const unsigned* __restrict__ maskT,             // [N/32][N]
        const __hip_bfloat16* __restrict__ WhB,          // [H][N/32][D/16][64][8]
        const float* __restrict__ C1g, const float* __restrict__ E2g,
        const float* __restrict__ S2g,
        float* __restrict__ outp) {
    constexpr int CTtot = D / 16;
    constexpr int CTT = CTtot / DSL;
    constexpr int CC = (D == 64) ? 1 : 2;
    constexpr int KSTEPS = N / (32 * G);
    static_assert(KSTEPS % 2 == 0, "two-step pipeline needs even KSTEPS");
    __shared__ float sh[MW * G * 16 * CC * 17];
    __shared__ float dsh[MW * G * 16];
    const int t = threadIdx.x;
    const int g = t >> 6, lane = t & 63;
    const int m = lane & 15, quad = lane >> 4;
    const int h = blockIdx.y / DSL, slc = blockIdx.y % DSL;
    const int i0 = blockIdx.x * (16 * MW);

    float c1v[MW];
#pragma unroll
    for (int mw = 0; mw < MW; mw++)
        c1v[mw] = C1g[(size_t)h * N + i0 + mw * 16 + m];

    // strength-reduced stream pointers
    const unsigned* mp = maskT + (size_t)(g * KSTEPS) * N + i0 + m;
    const float* ep = E2g + (size_t)h * N + g * (N / G) + quad * 8;
    const float* sp = S2g + (size_t)h * N + g * (N / G) + quad * 8;
    const bf16x8* bp = (const bf16x8*)WhB +
                       ((size_t)h * (N / 32) * CTtot +
                        (size_t)(g * KSTEPS) * CTtot + slc * CTT) * 64 + lane;

    const f32x4 zero = {0.f, 0.f, 0.f, 0.f};
    f32x4 acc[MW][CTT];
    f32x4 sac[MW];
#pragma unroll
    for (int mw = 0; mw < MW; mw++) {
        sac[mw] = zero;
#pragma unroll
        for (int ct = 0; ct < CTT; ct++) acc[mw][ct] = zero;
    }
    const short one_bf = (short)0x3F80;
    const bf16x8 ones = {one_bf, one_bf, one_bf, one_bf,
                         one_bf, one_bf, one_bf, one_bf};

    // ---- NAMED double-buffer state (no runtime indices anywhere) ----
    unsigned mwrdA[MW], mwrdB[MW];
    float4 e2loA, e2hiA, s2loA, s2hiA;
    float4 e2loB, e2hiB, s2loB, s2hiB;
    bf16x8 bfragA[CTT], bfragB[CTT];

    auto stage = [&](auto& mwrd_, float4& e2lo_, float4& e2hi_,
                     float4& s2lo_, float4& s2hi_, auto& bfrag_) {
#pragma unroll
        for (int mw = 0; mw < MW; mw++) mwrd_[mw] = mp[mw * 16];
        e2lo_ = *(const float4*)(ep);
        e2hi_ = *(const float4*)(ep + 4);
        s2lo_ = *(const float4*)(sp);
        s2hi_ = *(const float4*)(sp + 4);
#pragma unroll
        for (int ct = 0; ct < CTT; ct++) bfrag_[ct] = bp[ct * 64];
        mp += N; ep += 32; sp += 32; bp += CTtot * 64;
    };

    auto compute = [&](const auto& mwrd_, const float4& e2lo_,
                       const float4& e2hi_, const float4& s2lo_,
                       const float4& s2hi_, const auto& bfrag_) {
        const float Ee[8] = {e2lo_.x, e2lo_.y, e2lo_.z, e2lo_.w,
                             e2hi_.x, e2hi_.y, e2hi_.z, e2hi_.w};
        const float Se[8] = {s2lo_.x, s2lo_.y, s2lo_.z, s2lo_.w,
                             s2hi_.x, s2hi_.y, s2hi_.z, s2hi_.w};
        bf16x8 afr[MW];
#pragma unroll
        for (int mw = 0; mw < MW; mw++) {
            const unsigned mword = (mwrd_[mw] >> (quad * 8)) & 0xFFu;
            const unsigned spread = mword * 0x8001u;
            float p[8];
#pragma unroll
            for (int e = 0; e < 8; e++)
                p[e] = fmaxf(Ee[e], c1v[mw] * Se[e]);
            union { bf16x8 v; unsigned u32[4]; __hip_bfloat162 h2[4]; } u;
#pragma unroll
            for (int e2 = 0; e2 < 4; e2++) {
                u.h2[e2] = __float22bfloat162_rn(
                    make_float2(p[2 * e2], p[2 * e2 + 1]));
                const unsigned mk =
                    ((spread >> (2 * e2)) & 0x00010001u) * 0xFFFFu;
                u.u32[e2] &= mk;
            }
            afr[mw] = u.v;
        }
#pragma unroll
        for (int ct = 0; ct < CTT; ct++)
#pragma unroll
            for (int mw = 0; mw < MW; mw++)
                acc[mw][ct] = __builtin_amdgcn_mfma_f32_16x16x32_bf16(
                    afr[mw], bfrag_[ct], acc[mw][ct], 0, 0, 0);
#pragma unroll
        for (int mw = 0; mw < MW; mw++)
            sac[mw] = __builtin_amdgcn_mfma_f32_16x16x32_bf16(
                afr[mw], ones, sac[mw], 0, 0, 0);
    };

    stage(mwrdA, e2loA, e2hiA, s2loA, s2hiA, bfragA);
    for (int ks = 0; ks < KSTEPS; ks += 2) {
        stage(mwrdB, e2loB, e2hiB, s2loB, s2hiB, bfragB);   // prefetch odd
        compute(mwrdA, e2loA, e2hiA, s2loA, s2hiA, bfragA); // even step
        if (ks + 2 < KSTEPS)
            stage(mwrdA, e2loA, e2hiA, s2loA, s2hiA, bfragA); // prefetch even
        compute(mwrdB, e2loB, e2hiB, s2loB, s2hiB, bfragB); // odd step
    }

    // ---- epilogue: LDS cross-group reduction ----
#pragma unroll
    for (int rd = 0; rd < CTT / CC; rd++) {
#pragma unroll
        for (int mw = 0; mw < MW; mw++) {
#pragma unroll
            for (int cc = 0; cc < CC; cc++) {
#pragma unroll
                for (int r = 0; r < 4; r++)
                    sh[(((mw * G + g) * 16 + quad * 4 + r) * CC + cc) * 17 + m] =
                        acc[mw][rd * CC + cc][r];
            }
            if (rd == 0 && m == 0) {
#pragma unroll
                for (int r = 0; r < 4; r++)
                    dsh[(mw * G + g) * 16 + quad * 4 + r] = sac[mw][r];
            }
        }
        __syncthreads();
        if (t < 16 * CC * 16) {
            int row, chl;
            if (D == 64) { row = t & 15; chl = (t >> 4) & 15; }
            else         { chl = t & 31; row = (t >> 5) & 15; }
#pragma unroll
            for (int mw = 0; mw < MW; mw++) {
                float av = 0.f, ss = 0.f;
#pragma unroll
                for (int gg = 0; gg < G; gg++) {
                    av += sh[(((mw * G + gg) * 16 + row) * CC + (chl >> 4)) * 17 +
                             (chl & 15)];
                    ss += dsh[(mw * G + gg) * 16 + row];
                }
                float v = av / ss;
                v = (v > 0.f) ? v : (__builtin_amdgcn_exp2f(v * LOG2E) - 1.f);
                const int chg = h * D + slc * (CTT * 16) + rd * CC * 16 + chl;
                const int irow = i0 + mw * 16 + row;
                if (D == 64)
                    outp[(size_t)irow * (NHEADS * HID) + chg] = v;  // h1[i][ch]
                else
                    outp[(size_t)irow * D + chg] = v;               // out[i][ch]
            }
        }
        __syncthreads();
    }
}

// ---------------------------------------------------------------------------
// gemm2 via MFMA bf16-split: h1[4096][256] @ W2[256][128].
// Tail writes C1b / E2b / S2b for the E1-cancelled layer-2 P-gen.
// ---------------------------------------------------------------------------
__global__ __launch_bounds__(512, 2) void gemm2_kernel(
        const float* __restrict__ h1, const float* __restrict__ W2,
        const float* __restrict__ a2, __hip_bfloat16* __restrict__ WhB2,
        float* __restrict__ C1, float* __restrict__ E2, float* __restrict__ S2) {
    __shared__ float fred[8][16][2];
    const int t = threadIdx.x;
    const int w = t >> 6, lane = t & 63, m = lane & 15, quad = lane >> 4;
    const int i0 = blockIdx.x * 16;
    const float* arow = h1 + (size_t)(i0 + m) * IN_DIM;
    const float* wp = W2 + w * 16 + m;
    const f32x4 zero = {0.f, 0.f, 0.f, 0.f};
    f32x4 acc = zero;
    for (int ks = 0; ks < 8; ks++) {
        const int kb = ks * 32 + quad * 8;
        const float4 xa = *(const float4*)(arow + kb);
        const float4 xb = *(const float4*)(arow + kb + 4);
        const float xf[8] = {xa.x, xa.y, xa.z, xa.w, xb.x, xb.y, xb.z, xb.w};
        bf16x8 xh, xl, wh, wl;
#pragma unroll
        for (int e = 0; e < 8; e++) {
            const ushort2 s = bsplit(xf[e]);
            xh[e] = (short)s.x; xl[e] = (short)s.y;
        }
#pragma unroll
        for (int e = 0; e < 8; e++) {
            const ushort2 s = bsplit(wp[(size_t)(kb + e) * OUT_DIM]);
            wh[e] = (short)s.x; wl[e] = (short)s.y;
        }
        acc = __builtin_amdgcn_mfma_f32_16x16x32_bf16(xh, wh, acc, 0, 0, 0);
        acc = __builtin_amdgcn_mfma_f32_16x16x32_bf16(xl, wh, acc, 0, 0, 0);
        acc = __builtin_amdgcn_mfma_f32_16x16x32_bf16(xh, wl, acc, 0, 0, 0);
    }
    const int jblk = i0 >> 5, jb2 = (i0 >> 4) & 1;
#pragma unroll
    for (int r = 0; r < 4; r++) {
        const int jo = quad * 4 + r;
        const int lane_idx = m + 16 * (2 * jb2 + (jo >> 3));
        WhB2[(((size_t)jblk * 8 + w) * 64 + lane_idx) * 8 + (jo & 7)] =
            __float2bfloat16(acc[r]);
    }
    const float av1 = a2[w * 16 + m], av2 = a2[OUT_DIM + w * 16 + m];
    float s1[4], s2[4];
#pragma unroll
    for (int r = 0; r < 4; r++) { s1[r] = acc[r] * av1; s2[r] = acc[r] * av2; }
#pragma unroll
    for (int mm = 8; mm > 0; mm >>= 1) {
#pragma unroll
        for (int r = 0; r < 4; r++) {
            s1[r] += __shfl_xor(s1[r], mm, 64);
            s2[r] += __shfl_xor(s2[r], mm, 64);
        }
    }
    if (m == 0) {
#pragma unroll
        for (int r = 0; r < 4; r++) {
            fred[w][quad * 4 + r][0] = s1[r];
            fred[w][quad * 4 + r][1] = s2[r];
        }
    }
    __syncthreads();
    if (t < 32) {
        const int row = t & 15, fn = t >> 4;
        float s = 0.f;
#pragma unroll
        for (int w8 = 0; w8 < 8; w8++) s += fred[w8][row][fn];
        if (fn) {
            E2[i0 + row] = __builtin_amdgcn_exp2f(s * LOG2E);
            S2[i0 + row] = __builtin_amdgcn_exp2f(s * (0.5f * LOG2E));
        } else {
            C1[i0 + row] = __builtin_amdgcn_exp2f(s * (-0.5f * LOG2E));
        }
    }
}

// ---------------------------------------------------------------------------
extern "C" void kernel_launch(void* const* d_in, const int* in_sizes, int n_in,
                              void* d_out, int out_size, void* d_ws, size_t ws_size,
                              hipStream_t stream) {
    const float* x   = (const float*)d_in[0];
    const int*   adj = (const int*)d_in[1];
    const float* Wh_ = (const float*)d_in[2];
    const float* ah  = (const float*)d_in[3];
    const float* W2  = (const float*)d_in[4];
    const float* a2  = (const float*)d_in[5];
    float* out = (float*)d_out;

    float* ws = (float*)d_ws;
    float* C1a = ws;                                    // 4*N each
    float* E2a = C1a + (size_t)NHEADS * N;
    float* S2a = E2a + (size_t)NHEADS * N;
    float* C1b = S2a + (size_t)NHEADS * N;              // N each
    float* E2b = C1b + N;
    float* S2b = E2b + N;
    float* h1  = S2b + N;                               // N*256 fp32 (4MB)
    __hip_bfloat16* WhB1 = (__hip_bfloat16*)(h1 + (size_t)IN_DIM * N);  // 2MB
    __hip_bfloat16* WhB2 = WhB1 + (size_t)NHEADS * HID * N;            // 1MB
    unsigned* maskT = (unsigned*)(WhB2 + (size_t)OUT_DIM * N);         // 2MB

    prep_kernel<<<1280, 256, 0, stream>>>(x, Wh_, ah, adj, WhB1,
                                          C1a, E2a, S2a, maskT);
    attn_fused<NHEADS, HID, 1, 8, 2, 2>
        <<<dim3(N / 32, NHEADS), 512, 0, stream>>>(maskT, WhB1,
                                                   C1a, E2a, S2a, h1);
    gemm2_kernel<<<N / 16, 512, 0, stream>>>(h1, W2, a2, WhB2,
                                             C1b, E2b, S2b);
    attn_fused<1, OUT_DIM, 1, 8, 1, 2>
        <<<dim3(N / 16, 1), 512, 0, stream>>>(maskT, WhB2,
                                              C1b, E2b, S2b, out);
}